// Round 1
// baseline (278.904 us; speedup 1.0000x reference)
//
#include <hip/hip_runtime.h>
#include <math.h>

// KLDiracVMF: losses/l1/l2/l3 for vMF KL with Dirac, d=512, r=64, v=255.
// Structure: per-row dot(mu,wc) (memory-bound, 256MB) + 700-term log-space
// Bessel series (compute, hidden under memory). lgamma(k+1)+lgamma(k+256)
// is row-independent -> precomputed table in d_ws.

#define K_TERMS 700
#define ZD 512
#define VV 255.0f
// 256*log(2*pi) + 512*log(64)
#define CONST_TERM 2599.8446676805443f

__global__ void lg_table_kernel(float* __restrict__ lg) {
    int i = blockIdx.x * blockDim.x + threadIdx.x;
    if (i < K_TERMS) {
        double k = (double)i;
        // lgamma(k+1) + lgamma(k + v + 1), v = 255
        lg[i] = (float)(lgamma(k + 1.0) + lgamma(k + 256.0));
    }
}

__global__ __launch_bounds__(256) void vmf_kernel(
    const float* __restrict__ mu, const float* __restrict__ kappa,
    const float* __restrict__ wc, const float* __restrict__ lg,
    float* __restrict__ out, int B)
{
    const int wave = (int)((blockIdx.x * blockDim.x + threadIdx.x) >> 6);
    const int lane = (int)(threadIdx.x & 63);
    if (wave >= B) return;

    // ---- dot(mu_row, wc_row): lane i handles 8 contiguous floats ----
    const float4* m4 = (const float4*)(mu + (size_t)wave * ZD) + lane * 2;
    const float4* w4 = (const float4*)(wc + (size_t)wave * ZD) + lane * 2;
    float4 a0 = m4[0], a1 = m4[1];
    float4 b0 = w4[0], b1 = w4[1];
    float dp = a0.x * b0.x + a0.y * b0.y + a0.z * b0.z + a0.w * b0.w
             + a1.x * b1.x + a1.y * b1.y + a1.z * b1.z + a1.w * b1.w;
    #pragma unroll
    for (int off = 32; off >= 1; off >>= 1)
        dp += __shfl_xor(dp, off, 64);

    const float kap = kappa[wave];
    const float L  = logf(0.5f * kap);   // log(x/2)

    // ---- online logsumexp over t_k = 2k*L - lg[k], k = lane + 64*j ----
    float m = -3.4e38f, s = 0.0f;
    for (int k = lane; k < K_TERMS; k += 64) {
        float t = 2.0f * (float)k * L - lg[k];
        float nm = fmaxf(m, t);
        s = s * __expf(m - nm) + __expf(t - nm);
        m = nm;
    }
    // wave-level (m,s) merge via butterfly
    #pragma unroll
    for (int off = 32; off >= 1; off >>= 1) {
        float mo = __shfl_xor(m, off, 64);
        float so = __shfl_xor(s, off, 64);
        float nm = fmaxf(m, mo);
        s = s * __expf(m - nm) + so * __expf(mo - nm);
        m = nm;
    }
    const float lse = m + logf(s);

    // ---- assemble outputs ----
    const float log_ive      = VV * L + lse - kap;               // log(I_v(k)e^-k)
    const float log_ive_kap  = logf(1e-6f + __expf(log_ive));
    const float log_iv_kappa = log_ive_kap + kap;
    const float cos_theta    = dp * (1.0f / 64.0f);

    const float l1 = -kap * cos_theta;
    const float l2 = -VV * logf(1e-6f + kap);
    const float l3 = log_iv_kappa;
    const float losses = l1 + l2 + l3 + CONST_TERM;

    if (lane == 0) {
        out[wave]             = losses;
        out[(size_t)B + wave] = l1;
        out[(size_t)2 * B + wave] = l2;
        out[(size_t)3 * B + wave] = l3;
    }
}

extern "C" void kernel_launch(void* const* d_in, const int* in_sizes, int n_in,
                              void* d_out, int out_size, void* d_ws, size_t ws_size,
                              hipStream_t stream) {
    const float* mu    = (const float*)d_in[0];
    const float* kappa = (const float*)d_in[1];
    const float* wc    = (const float*)d_in[2];
    float* out = (float*)d_out;
    float* lg  = (float*)d_ws;   // K_TERMS floats of scratch
    const int B = in_sizes[1];   // kappa is [B,1]

    lg_table_kernel<<<(K_TERMS + 255) / 256, 256, 0, stream>>>(lg);
    // one wave per row, 4 waves per block
    vmf_kernel<<<(B + 3) / 4, 256, 0, stream>>>(mu, kappa, wc, lg, out, B);
}

// Round 2
// 276.871 us; speedup vs baseline: 1.0073x; 1.0073x over previous
//
#include <hip/hip_runtime.h>
#include <math.h>

// KLDiracVMF: losses/l1/l2/l3 for vMF KL with Dirac, d=512, r=64, v=255.
// R2: (a) lg-table via prefix-scan of logs (was: device double lgamma, ~180us
//     with only 3 blocks); (b) 256-term window around the series peak
//     k* = (sqrt(255^2+kappa^2)-255)/2 — edge terms are >=42 nats below max,
//     exact 0 in fp32; (c) two-pass logsumexp (max-reduce then sum-reduce)
//     replaces the serial online-rescale chain (34 -> ~10 exps/lane).

#define K_TERMS 700
#define WND 256            // series window (4 terms/lane)
#define ZD 512
#define VV 255.0f
// 256*log(2*pi) + 512*log(64)
#define CONST_TERM 2599.8446676805443f

__global__ __launch_bounds__(256) void lg_table_kernel(float* __restrict__ lg) {
    __shared__ double ssum[256];
    const int t = threadIdx.x;
    // lg[k] = lgamma(256) + sum_{j=1..k} (log j + log(j+255)); 3 entries/thread
    double loc[3];
    double tot = 0.0;
    #pragma unroll
    for (int i = 0; i < 3; ++i) {
        int p = t * 3 + i;                    // 0..767
        double inc = 0.0;
        if (p >= 1 && p < K_TERMS)
            inc = log((double)p) + log((double)(p + 255));
        tot += inc;
        loc[i] = tot;                         // inclusive prefix within thread
    }
    ssum[t] = tot;
    __syncthreads();
    // Kogge-Stone inclusive scan across the 256 per-thread totals
    for (int off = 1; off < 256; off <<= 1) {
        double v = (t >= off) ? ssum[t - off] : 0.0;
        __syncthreads();
        ssum[t] += v;
        __syncthreads();
    }
    const double excl = (t == 0) ? 0.0 : ssum[t - 1];
    // base = lgamma(256) via Stirling (z=256: error ~1e-13)
    const double z = 256.0;
    const double base = (z - 0.5) * log(z) - z + 0.918938533204672741780
                      + 1.0 / (12.0 * z) - 1.0 / (360.0 * z * z * z);
    #pragma unroll
    for (int i = 0; i < 3; ++i) {
        int p = t * 3 + i;
        if (p < K_TERMS) lg[p] = (float)(base + excl + loc[i]);
    }
}

__global__ __launch_bounds__(256) void vmf_kernel(
    const float* __restrict__ mu, const float* __restrict__ kappa,
    const float* __restrict__ wc, const float* __restrict__ lg,
    float* __restrict__ out, int B)
{
    const int wave = (int)((blockIdx.x * blockDim.x + threadIdx.x) >> 6);
    const int lane = (int)(threadIdx.x & 63);
    if (wave >= B) return;

    // ---- issue row loads early (memory in flight during series math) ----
    const float4* m4 = (const float4*)(mu + (size_t)wave * ZD) + lane * 2;
    const float4* w4 = (const float4*)(wc + (size_t)wave * ZD) + lane * 2;
    float4 a0 = m4[0], a1 = m4[1];
    float4 b0 = w4[0], b1 = w4[1];

    const float kap = kappa[wave];
    const float L   = logf(0.5f * kap);      // log(x/2)

    // ---- 256-term window centered at the series peak ----
    // k* solves 2L = psi(k+1)+psi(k+256)  =>  k(k+255) ~ (kap/2)^2
    const float kstar = 0.5f * (sqrtf(65025.0f + kap * kap) - 255.0f);
    int klo = (int)kstar - (WND / 2);
    klo = klo < 0 ? 0 : (klo > (K_TERMS - WND) ? (K_TERMS - WND) : klo);

    // ---- two-pass logsumexp: t_k independent, then max, then sum ----
    float t0, t1, t2, t3;
    {
        const int k0 = klo + lane;
        t0 = fmaf(2.0f * (float)(k0),        L, -lg[k0]);
        t1 = fmaf(2.0f * (float)(k0 + 64),   L, -lg[k0 + 64]);
        t2 = fmaf(2.0f * (float)(k0 + 128),  L, -lg[k0 + 128]);
        t3 = fmaf(2.0f * (float)(k0 + 192),  L, -lg[k0 + 192]);
    }
    float m = fmaxf(fmaxf(t0, t1), fmaxf(t2, t3));
    #pragma unroll
    for (int off = 32; off >= 1; off >>= 1)
        m = fmaxf(m, __shfl_xor(m, off, 64));
    float s = __expf(t0 - m) + __expf(t1 - m) + __expf(t2 - m) + __expf(t3 - m);
    #pragma unroll
    for (int off = 32; off >= 1; off >>= 1)
        s += __shfl_xor(s, off, 64);
    const float lse = m + logf(s);

    // ---- dot(mu_row, wc_row) ----
    float dp = a0.x * b0.x + a0.y * b0.y + a0.z * b0.z + a0.w * b0.w
             + a1.x * b1.x + a1.y * b1.y + a1.z * b1.z + a1.w * b1.w;
    #pragma unroll
    for (int off = 32; off >= 1; off >>= 1)
        dp += __shfl_xor(dp, off, 64);

    // ---- assemble outputs ----
    const float log_ive      = VV * L + lse - kap;               // log(I_v(k)e^-k)
    const float log_ive_kap  = logf(1e-6f + __expf(log_ive));
    const float log_iv_kappa = log_ive_kap + kap;
    const float cos_theta    = dp * (1.0f / 64.0f);

    const float l1 = -kap * cos_theta;
    const float l2 = -VV * logf(1e-6f + kap);
    const float l3 = log_iv_kappa;
    const float losses = l1 + l2 + l3 + CONST_TERM;

    if (lane == 0) {
        out[wave]                 = losses;
        out[(size_t)B + wave]     = l1;
        out[(size_t)2 * B + wave] = l2;
        out[(size_t)3 * B + wave] = l3;
    }
}

extern "C" void kernel_launch(void* const* d_in, const int* in_sizes, int n_in,
                              void* d_out, int out_size, void* d_ws, size_t ws_size,
                              hipStream_t stream) {
    const float* mu    = (const float*)d_in[0];
    const float* kappa = (const float*)d_in[1];
    const float* wc    = (const float*)d_in[2];
    float* out = (float*)d_out;
    float* lg  = (float*)d_ws;   // K_TERMS floats of scratch
    const int B = in_sizes[1];   // kappa is [B,1]

    lg_table_kernel<<<1, 256, 0, stream>>>(lg);
    // one wave per row, 4 waves per block
    vmf_kernel<<<(B + 3) / 4, 256, 0, stream>>>(mu, kappa, wc, lg, out, B);
}